// Round 3
// baseline (223.482 us; speedup 1.0000x reference)
//
#include <hip/hip_runtime.h>
#include <math.h>

#define SPAT  96
#define IMG   (SPAT*SPAT)        /* 9216    */
#define PLANE (SPAT*SPAT*SPAT)   /* 884736  */
#define TILE4 (IMG/4)            /* 2304 float4 chunks per (cc,d) tile */

// ---------------------------------------------------------------------------
// 4x4 matrix inverse (adjugate)
// ---------------------------------------------------------------------------
__device__ inline void invert4(const float m[16], float inv[16]) {
    inv[0]  =  m[5]*m[10]*m[15] - m[5]*m[11]*m[14] - m[9]*m[6]*m[15] + m[9]*m[7]*m[14] + m[13]*m[6]*m[11] - m[13]*m[7]*m[10];
    inv[4]  = -m[4]*m[10]*m[15] + m[4]*m[11]*m[14] + m[8]*m[6]*m[15] - m[8]*m[7]*m[14] - m[12]*m[6]*m[11] + m[12]*m[7]*m[10];
    inv[8]  =  m[4]*m[9]*m[15]  - m[4]*m[11]*m[13] - m[8]*m[5]*m[15] + m[8]*m[7]*m[13] + m[12]*m[5]*m[11] - m[12]*m[7]*m[9];
    inv[12] = -m[4]*m[9]*m[14]  + m[4]*m[10]*m[13] + m[8]*m[5]*m[14] - m[8]*m[6]*m[13] - m[12]*m[5]*m[10] + m[12]*m[6]*m[9];
    inv[1]  = -m[1]*m[10]*m[15] + m[1]*m[11]*m[14] + m[9]*m[2]*m[15] - m[9]*m[3]*m[14] - m[13]*m[2]*m[11] + m[13]*m[3]*m[10];
    inv[5]  =  m[0]*m[10]*m[15] - m[0]*m[11]*m[14] - m[8]*m[2]*m[15] + m[8]*m[3]*m[14] + m[12]*m[2]*m[11] - m[12]*m[3]*m[10];
    inv[9]  = -m[0]*m[9]*m[15]  + m[0]*m[11]*m[13] + m[8]*m[1]*m[15] - m[8]*m[3]*m[13] - m[12]*m[1]*m[11] + m[12]*m[3]*m[9];
    inv[13] =  m[0]*m[9]*m[14]  - m[0]*m[10]*m[13] - m[8]*m[1]*m[14] + m[8]*m[2]*m[13] + m[12]*m[1]*m[10] - m[12]*m[2]*m[9];
    inv[2]  =  m[1]*m[6]*m[15]  - m[1]*m[7]*m[14]  - m[5]*m[2]*m[15] + m[5]*m[3]*m[14] + m[13]*m[2]*m[7]  - m[13]*m[3]*m[6];
    inv[6]  = -m[0]*m[6]*m[15]  + m[0]*m[7]*m[14]  + m[4]*m[2]*m[15] - m[4]*m[3]*m[14] - m[12]*m[2]*m[7]  + m[12]*m[3]*m[6];
    inv[10] =  m[0]*m[5]*m[15]  - m[0]*m[7]*m[13]  - m[4]*m[1]*m[15] + m[4]*m[3]*m[13] + m[12]*m[1]*m[7]  - m[12]*m[3]*m[5];
    inv[14] = -m[0]*m[5]*m[14]  + m[0]*m[6]*m[13]  + m[4]*m[1]*m[14] - m[4]*m[2]*m[13] - m[12]*m[1]*m[6]  + m[12]*m[2]*m[5];
    inv[3]  = -m[1]*m[6]*m[11]  + m[1]*m[7]*m[10]  + m[5]*m[2]*m[11] - m[5]*m[3]*m[10] - m[9]*m[2]*m[7]   + m[9]*m[3]*m[6];
    inv[7]  =  m[0]*m[6]*m[11]  - m[0]*m[7]*m[10]  - m[4]*m[2]*m[11] + m[4]*m[3]*m[10] + m[8]*m[2]*m[7]   - m[8]*m[3]*m[6];
    inv[11] = -m[0]*m[5]*m[11]  + m[0]*m[7]*m[9]   + m[4]*m[1]*m[11] - m[4]*m[3]*m[9]  - m[8]*m[1]*m[7]   + m[8]*m[3]*m[5];
    inv[15] =  m[0]*m[5]*m[10]  - m[0]*m[6]*m[9]   - m[4]*m[1]*m[10] + m[4]*m[2]*m[9]  + m[8]*m[1]*m[6]   - m[8]*m[2]*m[5];
    float det  = m[0]*inv[0] + m[1]*inv[4] + m[2]*inv[8] + m[3]*inv[12];
    float rdet = 1.0f / det;
    for (int i = 0; i < 16; ++i) inv[i] *= rdet;
}

// ---------------------------------------------------------------------------
// Single-pass kernel, LDS-composed tile. blockIdx = (d, cc).
//  P0: zero 36KB LDS tile (ds_write only) + thread0 folds affine into Ms.
//  barrier (no VMEM outstanding -> cheap, no store-drain serialization)
//  P1: threads 0..95: closed-form w-interval for h-row, trilinear-sample
//      the ~1-2 contributing chunks into LDS (img reads are L2-hot).
//  barrier (cheap)
//  P2: branch-free stream copy LDS -> global, 9 x (ds_read_b128 + store)
//      per thread, coalesced; EVERY output line written exactly once with
//      final content => no L2-evict/RMW double traffic (the fused2 bug).
// ---------------------------------------------------------------------------
__global__ __launch_bounds__(256) void fused3_kernel(
        const float* __restrict__ xin,   // [2,32,96,96]
        const float* __restrict__ aff_in,// [2,2,4,4]
        float4* __restrict__ out) {      // [2,32,96,96,96] as float4 chunks
    __shared__ float4 tile[TILE4];       // 36864 B
    __shared__ float  Ms[12];
    const int tid = (int)threadIdx.x;
    const int d   = blockIdx.x;          // 0..95
    const int cc  = blockIdx.y;          // 0..63 = b*32 + c
    const int b   = cc >> 5;
    const int s   = (cc >> 4) & 1;
    const int sb  = s * 2 + b;

    // ---- P0: fold affine (thread 0) + zero the LDS tile (all threads) ----
    if (tid == 0) {
        float A[16];
        #pragma unroll
        for (int i = 0; i < 16; ++i) A[i] = aff_in[sb * 16 + i];
        #pragma unroll
        for (int j = 0; j < 3; ++j) {    // column-normalize by zooms
            float z = sqrtf(A[0*4+j]*A[0*4+j] + A[1*4+j]*A[1*4+j] + A[2*4+j]*A[2*4+j]);
            float rz = 1.0f / z;
            #pragma unroll
            for (int i = 0; i < 4; ++i) A[i*4+j] *= rz;
        }
        float inv[16];
        invert4(A, inv);
        #pragma unroll
        for (int r = 0; r < 3; ++r) {
            float T0 = inv[r*4+0], T1 = inv[r*4+1], T2 = inv[r*4+2], T3 = inv[r*4+3];
            // i_r = T0*w + T1*h + T2*d + [-47.5*(T0+T1+T2) + 48*T3 + 47.5]
            Ms[r*4+0] = T0;
            Ms[r*4+1] = T1;
            Ms[r*4+2] = T2;
            Ms[r*4+3] = -47.5f * (T0 + T1 + T2) + 48.0f * T3 + 47.5f;
        }
    }
    const float4 z4 = make_float4(0.f, 0.f, 0.f, 0.f);
    #pragma unroll
    for (int it = 0; it < 9; ++it)
        tile[tid + 256 * it] = z4;

    __syncthreads();   // lgkm-only drain: no global stores issued yet

    // ---- P1: sparse trilinear sampling into LDS, one h-row per thread ----
    if (tid < SPAT) {
        const int h = tid;
        const float Mxw = Ms[0], Mxh = Ms[1], Mxd = Ms[2],  Mx0 = Ms[3];
        const float Myw = Ms[4], Myh = Ms[5], Myd = Ms[6],  My0 = Ms[7];
        const float Mzw = Ms[8], Mzh = Ms[9], Mzd = Ms[10], Mz0 = Ms[11];

        const float fh = (float)h, fd = (float)d;
        const float bx = Mxh * fh + Mxd * fd + Mx0;

        // contributing w interval: |Mxw*w + bx - 48| < 1
        int wlo, whi;
        if (fabsf(Mxw) > 1e-6f) {
            float rMxw = 1.0f / Mxw;
            float w1 = (47.0f - bx) * rMxw;
            float w2 = (49.0f - bx) * rMxw;
            float wmin = fminf(w1, w2), wmax = fmaxf(w1, w2);
            wlo = max((int)ceilf(wmin), 0);
            whi = min((int)floorf(wmax), SPAT - 1);
        } else {
            bool in = fabsf(bx - 48.0f) < 1.0f;
            wlo = in ? 0 : 1;
            whi = in ? SPAT - 1 : 0;
        }
        if (wlo <= whi) {
            const float by = Myh * fh + Myd * fd + My0;
            const float bz = Mzh * fh + Mzd * fd + Mz0;
            const float* img = xin + (size_t)cc * IMG;

            const int qlo = wlo >> 2, qhi = whi >> 2;
            for (int q = qlo; q <= qhi; ++q) {
                float vv[4];
                #pragma unroll
                for (int j = 0; j < 4; ++j) {
                    float fw = (float)(4 * q + j);
                    float ix = Mxw * fw + bx;
                    float wx = 1.0f - fabsf(ix - 48.0f);
                    float r = 0.0f;
                    if (wx > 0.0f) {
                        float iy = Myw * fw + by;
                        float iz = Mzw * fw + bz;
                        float yf = floorf(iy), zf = floorf(iz);
                        float fy = iy - yf,    fz = iz - zf;
                        int y0 = (int)yf, z0 = (int)zf;
                        bool vy0 = (y0 >= 0)  & (y0 <  SPAT);
                        bool vy1 = (y0 >= -1) & (y0 <  SPAT - 1);
                        bool vz0 = (z0 >= 0)  & (z0 <  SPAT);
                        bool vz1 = (z0 >= -1) & (z0 <  SPAT - 1);
                        int y0c = min(max(y0, 0),     SPAT - 1);
                        int y1c = min(max(y0 + 1, 0), SPAT - 1);
                        int z0c = min(max(z0, 0),     SPAT - 1);
                        int z1c = min(max(z0 + 1, 0), SPAT - 1);
                        float wy0 = 1.0f - fy, wy1 = fy;
                        float wz0 = 1.0f - fz, wz1 = fz;
                        float w00 = wx * wz0 * wy0 * ((vz0 & vy0) ? 1.0f : 0.0f);
                        float w01 = wx * wz0 * wy1 * ((vz0 & vy1) ? 1.0f : 0.0f);
                        float w10 = wx * wz1 * wy0 * ((vz1 & vy0) ? 1.0f : 0.0f);
                        float w11 = wx * wz1 * wy1 * ((vz1 & vy1) ? 1.0f : 0.0f);
                        r = w00 * img[z0c * SPAT + y0c] + w01 * img[z0c * SPAT + y1c]
                          + w10 * img[z1c * SPAT + y0c] + w11 * img[z1c * SPAT + y1c];
                    }
                    vv[j] = r;
                }
                tile[h * 24 + q] = make_float4(vv[0], vv[1], vv[2], vv[3]);
            }
        }
    }

    __syncthreads();   // lgkm-only again (sampling loads retired by use)

    // ---- P2: branch-free stream copy LDS -> global, lines written once ----
    float4* op = out + ((size_t)cc * (PLANE / 4) + (size_t)d * (IMG / 4));
    #pragma unroll
    for (int it = 0; it < 9; ++it)
        op[tid + 256 * it] = tile[tid + 256 * it];
}

extern "C" void kernel_launch(void* const* d_in, const int* in_sizes, int n_in,
                              void* d_out, int out_size, void* d_ws, size_t ws_size,
                              hipStream_t stream) {
    const float* x   = (const float*)d_in[0];   // [2,32,96,96] fp32
    const float* aff = (const float*)d_in[1];   // [2,2,4,4]    fp32
    float* out = (float*)d_out;                 // [2,32,96,96,96] fp32

    dim3 grid(SPAT, 64);                        // (d, b*32+c); one pass total
    fused3_kernel<<<grid, 256, 0, stream>>>(x, aff, (float4*)out);
}

// Round 4
// 220.264 us; speedup vs baseline: 1.0146x; 1.0146x over previous
//
#include <hip/hip_runtime.h>
#include <math.h>

#define SPAT  96
#define IMG   (SPAT*SPAT)        /* 9216    */
#define PLANE (SPAT*SPAT*SPAT)   /* 884736  */
#define HROWS 48                 /* h-rows per block (half tile) */
#define HCHUNK (HROWS*24)        /* 1152 float4 chunks = 18 KB   */

// ---------------------------------------------------------------------------
// 4x4 matrix inverse (adjugate)
// ---------------------------------------------------------------------------
__device__ inline void invert4(const float m[16], float inv[16]) {
    inv[0]  =  m[5]*m[10]*m[15] - m[5]*m[11]*m[14] - m[9]*m[6]*m[15] + m[9]*m[7]*m[14] + m[13]*m[6]*m[11] - m[13]*m[7]*m[10];
    inv[4]  = -m[4]*m[10]*m[15] + m[4]*m[11]*m[14] + m[8]*m[6]*m[15] - m[8]*m[7]*m[14] - m[12]*m[6]*m[11] + m[12]*m[7]*m[10];
    inv[8]  =  m[4]*m[9]*m[15]  - m[4]*m[11]*m[13] - m[8]*m[5]*m[15] + m[8]*m[7]*m[13] + m[12]*m[5]*m[11] - m[12]*m[7]*m[9];
    inv[12] = -m[4]*m[9]*m[14]  + m[4]*m[10]*m[13] + m[8]*m[5]*m[14] - m[8]*m[6]*m[13] - m[12]*m[5]*m[10] + m[12]*m[6]*m[9];
    inv[1]  = -m[1]*m[10]*m[15] + m[1]*m[11]*m[14] + m[9]*m[2]*m[15] - m[9]*m[3]*m[14] - m[13]*m[2]*m[11] + m[13]*m[3]*m[10];
    inv[5]  =  m[0]*m[10]*m[15] - m[0]*m[11]*m[14] - m[8]*m[2]*m[15] + m[8]*m[3]*m[14] + m[12]*m[2]*m[11] - m[12]*m[3]*m[10];
    inv[9]  = -m[0]*m[9]*m[15]  + m[0]*m[11]*m[13] + m[8]*m[1]*m[15] - m[8]*m[3]*m[13] - m[12]*m[1]*m[11] + m[12]*m[3]*m[9];
    inv[13] =  m[0]*m[9]*m[14]  - m[0]*m[10]*m[13] - m[8]*m[1]*m[14] + m[8]*m[2]*m[13] + m[12]*m[1]*m[10] - m[12]*m[2]*m[9];
    inv[2]  =  m[1]*m[6]*m[15]  - m[1]*m[7]*m[14]  - m[5]*m[2]*m[15] + m[5]*m[3]*m[14] + m[13]*m[2]*m[7]  - m[13]*m[3]*m[6];
    inv[6]  = -m[0]*m[6]*m[15]  + m[0]*m[7]*m[14]  + m[4]*m[2]*m[15] - m[4]*m[3]*m[14] - m[12]*m[2]*m[7]  + m[12]*m[3]*m[6];
    inv[10] =  m[0]*m[5]*m[15]  - m[0]*m[7]*m[13]  - m[4]*m[1]*m[15] + m[4]*m[3]*m[13] + m[12]*m[1]*m[7]  - m[12]*m[3]*m[5];
    inv[14] = -m[0]*m[5]*m[14]  + m[0]*m[6]*m[13]  + m[4]*m[1]*m[14] - m[4]*m[2]*m[13] - m[12]*m[1]*m[6]  + m[12]*m[2]*m[5];
    inv[3]  = -m[1]*m[6]*m[11]  + m[1]*m[7]*m[10]  + m[5]*m[2]*m[11] - m[5]*m[3]*m[10] - m[9]*m[2]*m[7]   + m[9]*m[3]*m[6];
    inv[7]  =  m[0]*m[6]*m[11]  - m[0]*m[7]*m[10]  - m[4]*m[2]*m[11] + m[4]*m[3]*m[10] + m[8]*m[2]*m[7]   - m[8]*m[3]*m[6];
    inv[11] = -m[0]*m[5]*m[11]  + m[0]*m[7]*m[9]   + m[4]*m[1]*m[11] - m[4]*m[3]*m[9]  - m[8]*m[1]*m[7]   + m[8]*m[3]*m[5];
    inv[15] =  m[0]*m[5]*m[10]  - m[0]*m[6]*m[9]   - m[4]*m[1]*m[10] + m[4]*m[2]*m[9]  + m[8]*m[1]*m[6]   - m[8]*m[2]*m[5];
    float det  = m[0]*inv[0] + m[1]*inv[4] + m[2]*inv[8] + m[3]*inv[12];
    float rdet = 1.0f / det;
    for (int i = 0; i < 16; ++i) inv[i] *= rdet;
}

// ---------------------------------------------------------------------------
// Half-tile LDS-compose kernel. blockIdx = (d*2+hhalf, cc). 18 KB LDS.
//  - all threads fold the affine redundantly in regs (no serial thread-0,
//    no LDS broadcast, no barrier dependency)
//  - sampler threads t<96 = (row rr=t>>1, k=t&1) own chunk qlo+k of their
//    h-row; the 16 trilinear taps are issued as one independent load batch
//    BEFORE the LDS-zero phase (one latency wait, partially covered)
//  - all threads zero the 18 KB tile; barrier (lgkm-only)
//  - samplers recompute weights (cheap VALU) and compose their chunk into
//    LDS; rare fallback loop for q>=qlo+2; barrier
//  - branch-free coalesced stream LDS -> global, every line written once
// ---------------------------------------------------------------------------
__global__ __launch_bounds__(256, 4) void fused4_kernel(
        const float* __restrict__ xin,   // [2,32,96,96]
        const float* __restrict__ aff_in,// [2,2,4,4]
        float4* __restrict__ out) {      // [2,32,96,96,96] as float4 chunks
    __shared__ float4 tile[HCHUNK];      // 18432 B
    const int tid = (int)threadIdx.x;
    const int dh2 = blockIdx.x;          // 0..191
    const int d   = dh2 >> 1;
    const int hh  = dh2 & 1;             // which h-half
    const int cc  = blockIdx.y;          // 0..63 = b*32 + c
    const int b   = cc >> 5;
    const int s   = (cc >> 4) & 1;
    const int sb  = s * 2 + b;

    // ---- fold affine: every thread, in registers (ILP-parallel) ----
    float M[12];
    {
        float A[16];
        #pragma unroll
        for (int i = 0; i < 16; ++i) A[i] = aff_in[sb * 16 + i];
        #pragma unroll
        for (int j = 0; j < 3; ++j) {    // column-normalize by zooms
            float z = sqrtf(A[0*4+j]*A[0*4+j] + A[1*4+j]*A[1*4+j] + A[2*4+j]*A[2*4+j]);
            float rz = 1.0f / z;
            #pragma unroll
            for (int i = 0; i < 4; ++i) A[i*4+j] *= rz;
        }
        float inv[16];
        invert4(A, inv);
        #pragma unroll
        for (int r = 0; r < 3; ++r) {
            float T0 = inv[r*4+0], T1 = inv[r*4+1], T2 = inv[r*4+2], T3 = inv[r*4+3];
            // i_r = T0*w + T1*h + T2*d + [-47.5*(T0+T1+T2) + 48*T3 + 47.5]
            M[r*4+0] = T0;
            M[r*4+1] = T1;
            M[r*4+2] = T2;
            M[r*4+3] = -47.5f * (T0 + T1 + T2) + 48.0f * T3 + 47.5f;
        }
    }
    const float Mxw = M[0], Mxh = M[1], Mxd = M[2],  Mx0 = M[3];
    const float Myw = M[4], Myh = M[5], Myd = M[6],  My0 = M[7];
    const float Mzw = M[8], Mzh = M[9], Mzd = M[10], Mz0 = M[11];

    const float* img = xin + (size_t)cc * IMG;

    // ---- sampler prelude: compute interval, ISSUE all 16 taps now ----
    float tv[16];
    float bx = 0.f, by = 0.f, bz = 0.f;
    int   rr = 0, myq = 0, fqlo = 0, fqhi = -1;
    bool  act = false;
    if (tid < 2 * HROWS) {
        rr = tid >> 1;                   // LDS row 0..47
        const int k = tid & 1;
        const int h = hh * HROWS + rr;
        const float fh = (float)h, fd = (float)d;
        bx = Mxh * fh + Mxd * fd + Mx0;
        by = Myh * fh + Myd * fd + My0;
        bz = Mzh * fh + Mzd * fd + Mz0;

        int wlo, whi;
        if (fabsf(Mxw) > 1e-6f) {
            float rMxw = 1.0f / Mxw;
            float w1 = (47.0f - bx) * rMxw;
            float w2 = (49.0f - bx) * rMxw;
            float wmin = fminf(w1, w2), wmax = fmaxf(w1, w2);
            wlo = max((int)ceilf(wmin), 0);
            whi = min((int)floorf(wmax), SPAT - 1);
        } else {
            bool in = fabsf(bx - 48.0f) < 1.0f;
            wlo = in ? 0 : 1;
            whi = in ? SPAT - 1 : 0;
        }
        const int qlo = wlo >> 2, qhi = whi >> 2;
        myq = qlo + k;
        if (wlo <= whi && myq <= qhi) {
            act = true;
            #pragma unroll
            for (int j = 0; j < 4; ++j) {
                float fw = (float)(4 * myq + j);
                float ix = Mxw * fw + bx;
                float wx = 1.0f - fabsf(ix - 48.0f);
                if (wx > 0.0f) {
                    float iy = Myw * fw + by;
                    float iz = Mzw * fw + bz;
                    int y0 = (int)floorf(iy), z0 = (int)floorf(iz);
                    int y0c = min(max(y0, 0),     SPAT - 1);
                    int y1c = min(max(y0 + 1, 0), SPAT - 1);
                    int z0c = min(max(z0, 0),     SPAT - 1);
                    int z1c = min(max(z0 + 1, 0), SPAT - 1);
                    tv[4*j+0] = img[z0c * SPAT + y0c];
                    tv[4*j+1] = img[z0c * SPAT + y1c];
                    tv[4*j+2] = img[z1c * SPAT + y0c];
                    tv[4*j+3] = img[z1c * SPAT + y1c];
                } else {
                    tv[4*j+0] = 0.f; tv[4*j+1] = 0.f;
                    tv[4*j+2] = 0.f; tv[4*j+3] = 0.f;
                }
            }
        }
        if (k == 1 && wlo <= whi) { fqlo = qlo + 2; fqhi = qhi; }  // rare
    }

    // ---- zero the LDS half-tile (covers part of the load latency) ----
    const float4 z4 = make_float4(0.f, 0.f, 0.f, 0.f);
    #pragma unroll
    for (int i = tid; i < HCHUNK; i += 256) tile[i] = z4;

    __syncthreads();

    // ---- compose: recompute weights (VALU), consume prefetched taps ----
    if (act) {
        float vv[4];
        #pragma unroll
        for (int j = 0; j < 4; ++j) {
            float fw = (float)(4 * myq + j);
            float ix = Mxw * fw + bx;
            float wx = 1.0f - fabsf(ix - 48.0f);
            float r = 0.0f;
            if (wx > 0.0f) {
                float iy = Myw * fw + by;
                float iz = Mzw * fw + bz;
                float yf = floorf(iy), zf = floorf(iz);
                float fy = iy - yf,    fz = iz - zf;
                int y0 = (int)yf, z0 = (int)zf;
                bool vy0 = (y0 >= 0)  & (y0 <  SPAT);
                bool vy1 = (y0 >= -1) & (y0 <  SPAT - 1);
                bool vz0 = (z0 >= 0)  & (z0 <  SPAT);
                bool vz1 = (z0 >= -1) & (z0 <  SPAT - 1);
                float wy0 = 1.0f - fy, wy1 = fy;
                float wz0 = 1.0f - fz, wz1 = fz;
                float w00 = wx * wz0 * wy0 * ((vz0 & vy0) ? 1.0f : 0.0f);
                float w01 = wx * wz0 * wy1 * ((vz0 & vy1) ? 1.0f : 0.0f);
                float w10 = wx * wz1 * wy0 * ((vz1 & vy0) ? 1.0f : 0.0f);
                float w11 = wx * wz1 * wy1 * ((vz1 & vy1) ? 1.0f : 0.0f);
                r = w00 * tv[4*j+0] + w01 * tv[4*j+1]
                  + w10 * tv[4*j+2] + w11 * tv[4*j+3];
            }
            vv[j] = r;
        }
        tile[rr * 24 + myq] = make_float4(vv[0], vv[1], vv[2], vv[3]);
    }
    // rare fallback: interval spans >=3 chunks (k==1 thread mops up)
    for (int q = fqlo; q <= fqhi; ++q) {
        float vv[4];
        #pragma unroll
        for (int j = 0; j < 4; ++j) {
            float fw = (float)(4 * q + j);
            float ix = Mxw * fw + bx;
            float wx = 1.0f - fabsf(ix - 48.0f);
            float r = 0.0f;
            if (wx > 0.0f) {
                float iy = Myw * fw + by;
                float iz = Mzw * fw + bz;
                float yf = floorf(iy), zf = floorf(iz);
                float fy = iy - yf,    fz = iz - zf;
                int y0 = (int)yf, z0 = (int)zf;
                bool vy0 = (y0 >= 0)  & (y0 <  SPAT);
                bool vy1 = (y0 >= -1) & (y0 <  SPAT - 1);
                bool vz0 = (z0 >= 0)  & (z0 <  SPAT);
                bool vz1 = (z0 >= -1) & (z0 <  SPAT - 1);
                int y0c = min(max(y0, 0),     SPAT - 1);
                int y1c = min(max(y0 + 1, 0), SPAT - 1);
                int z0c = min(max(z0, 0),     SPAT - 1);
                int z1c = min(max(z0 + 1, 0), SPAT - 1);
                float wy0 = 1.0f - fy, wy1 = fy;
                float wz0 = 1.0f - fz, wz1 = fz;
                float w00 = wx * wz0 * wy0 * ((vz0 & vy0) ? 1.0f : 0.0f);
                float w01 = wx * wz0 * wy1 * ((vz0 & vy1) ? 1.0f : 0.0f);
                float w10 = wx * wz1 * wy0 * ((vz1 & vy0) ? 1.0f : 0.0f);
                float w11 = wx * wz1 * wy1 * ((vz1 & vy1) ? 1.0f : 0.0f);
                r = w00 * img[z0c * SPAT + y0c] + w01 * img[z0c * SPAT + y1c]
                  + w10 * img[z1c * SPAT + y0c] + w11 * img[z1c * SPAT + y1c];
            }
            vv[j] = r;
        }
        tile[rr * 24 + q] = make_float4(vv[0], vv[1], vv[2], vv[3]);
    }

    __syncthreads();

    // ---- branch-free coalesced stream LDS -> global ----
    float4* op = out + ((size_t)cc * (PLANE / 4) + (size_t)d * (IMG / 4)
                        + (size_t)hh * HCHUNK);
    #pragma unroll
    for (int i = tid; i < HCHUNK; i += 256) op[i] = tile[i];
}

extern "C" void kernel_launch(void* const* d_in, const int* in_sizes, int n_in,
                              void* d_out, int out_size, void* d_ws, size_t ws_size,
                              hipStream_t stream) {
    const float* x   = (const float*)d_in[0];   // [2,32,96,96] fp32
    const float* aff = (const float*)d_in[1];   // [2,2,4,4]    fp32
    float* out = (float*)d_out;                 // [2,32,96,96,96] fp32

    dim3 grid(2 * SPAT, 64);                    // (d*2+hhalf, b*32+c)
    fused4_kernel<<<grid, 256, 0, stream>>>(x, aff, (float4*)out);
}